// Round 1
// baseline (4796.337 us; speedup 1.0000x reference)
//
#include <hip/hip_runtime.h>
#include <stdint.h>

#define B_ 64
#define T_ 512
#define V_ 50000
#define E_ 256
#define H_ 256
#define L_ 9
#define BT (B_*T_)      // 32768
#define G4 (4*H_)       // 1024 gate rows per direction
#define N2 (2*G4)       // 2048 (both directions fused as GEMM N)

typedef short    bf16x8  __attribute__((ext_vector_type(8)));
typedef float    f32x4   __attribute__((ext_vector_type(4)));
typedef _Float16 half2_t __attribute__((ext_vector_type(2)));
typedef _Float16 half8   __attribute__((ext_vector_type(8)));

__device__ __forceinline__ unsigned short f2bf(float x){
    unsigned u = __builtin_bit_cast(unsigned, x);
    u += 0x7fffu + ((u >> 16) & 1u);          // round-to-nearest-even
    return (unsigned short)(u >> 16);
}
__device__ __forceinline__ float bf2f(unsigned short h){
    unsigned u = ((unsigned)h) << 16;
    return __builtin_bit_cast(float, u);
}

#if __has_builtin(__builtin_amdgcn_fdot2)
__device__ __forceinline__ float fdot2(half2_t a, half2_t b, float c){
    return __builtin_amdgcn_fdot2(a, b, c, false);
}
#else
__device__ __forceinline__ float fdot2(half2_t a, half2_t b, float c){
    return c + (float)a.x * (float)b.x + (float)a.y * (float)b.y;
}
#endif

__device__ __forceinline__ void lds_load16(void* lds, const void* g){
    __builtin_amdgcn_global_load_lds(
        (const __attribute__((address_space(1))) void*)g,
        (__attribute__((address_space(3))) void*)lds, 16, 0, 0);
}

__device__ __forceinline__ void store_out(unsigned short* p, float v){ *p = f2bf(v); }
__device__ __forceinline__ void store_out(float* p, float v){ *p = v; }

// ---------------- embedding gather: x0[bt][e] = bf16(emb[ids[bt]][e]) ----------------
__global__ void k_embed(const int* __restrict__ ids, const float* __restrict__ emb,
                        unsigned short* __restrict__ x0){
    int bt = blockIdx.x;
    int e  = threadIdx.x;
    int id = ids[bt];
    x0[(size_t)bt*E_ + e] = f2bf(emb[(size_t)id*E_ + e]);
}

// ---------------- fp32 -> bf16 pack ----------------
__global__ void k_pack_bf16(const float* __restrict__ in, unsigned short* __restrict__ out, int n){
    int i = blockIdx.x*256 + threadIdx.x;
    if (i < n) out[i] = f2bf(in[i]);
}

// w_hh [2][1024][256] fp32 -> packed fp16 [dir][k8(32)][g(1024)][8]
__global__ void k_pack_whh(const float* __restrict__ w, _Float16* __restrict__ out){
    int idx = blockIdx.x*256 + threadIdx.x;   // 65536 total
    int k8  = idx & 31;
    int g   = (idx >> 5) & 1023;
    int dir = idx >> 15;
    const float* s = w + ((size_t)(dir*G4 + g))*H_ + k8*8;
    _Float16* d = out + (((size_t)dir*32 + k8)*G4 + g)*8;
    #pragma unroll
    for (int q = 0; q < 8; ++q) d[q] = (_Float16)s[q];
}

// ---------------- bf16 MFMA GEMM: C[M][N] = A[M][K] * Bm[N][K]^T (bf16 out) ----------------
// 128x128 tile, 4 waves (2x2), each wave 64x64 = 4x4 frags of 16x16x32.
__global__ __launch_bounds__(256) void k_gemm(const unsigned short* __restrict__ A,
                                              const unsigned short* __restrict__ Bm,
                                              unsigned short* __restrict__ C,
                                              int M, int N, int K){
    __shared__ unsigned short As[128*32];
    __shared__ unsigned short Bs[128*32];
    int tid = threadIdx.x, lane = tid & 63, w = tid >> 6;
    int wm = w >> 1, wn = w & 1;
    int tileM = blockIdx.y * 128, tileN = blockIdx.x * 128;
    f32x4 acc[4][4] = {};
    const char* Ab = (const char*)A;
    const char* Bb = (const char*)Bm;
    for (int k0 = 0; k0 < K; k0 += 32){
        #pragma unroll
        for (int i = 0; i < 2; ++i){
            int off = (w*2 + i)*1024 + lane*16;   // byte offset within the 8KB tile
            int row = off >> 6, colb = off & 63;  // 64B per tile row (32 bf16)
            lds_load16((char*)As + (w*2+i)*1024,
                       Ab + ((size_t)(tileM + row)*K + k0)*2 + colb);
            lds_load16((char*)Bs + (w*2+i)*1024,
                       Bb + ((size_t)(tileN + row)*K + k0)*2 + colb);
        }
        __syncthreads();   // drains vmcnt for global_load_lds
        int kloc = (lane >> 4) * 8;
        bf16x8 af[4], bfv[4];
        #pragma unroll
        for (int mf = 0; mf < 4; ++mf)
            af[mf] = *(const bf16x8*)&As[(wm*64 + mf*16 + (lane & 15))*32 + kloc];
        #pragma unroll
        for (int nf = 0; nf < 4; ++nf)
            bfv[nf] = *(const bf16x8*)&Bs[(wn*64 + nf*16 + (lane & 15))*32 + kloc];
        #pragma unroll
        for (int mf = 0; mf < 4; ++mf)
            #pragma unroll
            for (int nf = 0; nf < 4; ++nf)
                acc[mf][nf] = __builtin_amdgcn_mfma_f32_16x16x32_bf16(
                                  af[mf], bfv[nf], acc[mf][nf], 0, 0, 0);
        __syncthreads();
    }
    #pragma unroll
    for (int mf = 0; mf < 4; ++mf){
        #pragma unroll
        for (int nf = 0; nf < 4; ++nf){
            int row0 = tileM + wm*64 + mf*16 + (lane >> 4)*4;
            int col  = tileN + wn*64 + nf*16 + (lane & 15);
            #pragma unroll
            for (int r = 0; r < 4; ++r)
                C[(size_t)(row0 + r)*N + col] = f2bf(acc[mf][nf][r]);
        }
    }
}

// ---------------- LSTM recurrence ----------------
// grid = B*2 blocks (batch, dir), block = 1024 threads (thread j = gate row j).
// gx: bf16 [BT][2048] (col = dir*1024+g). whh: packed fp16 [dir][32][1024][8].
// out: [BT][512], fwd cols 0..255, bwd cols 256..511.
template<typename OutT>
__global__ __launch_bounds__(1024) void k_rec(const unsigned short* __restrict__ gx,
                                              const _Float16* __restrict__ whh,
                                              const float* __restrict__ bias,
                                              OutT* __restrict__ out){
    int b = blockIdx.x >> 1, dir = blockIdx.x & 1;
    int j = threadIdx.x;
    __shared__ float gates[G4];
    __shared__ __align__(16) _Float16 hbuf[H_];
    if (j < H_) hbuf[j] = (_Float16)0.f;
    float c  = 0.f;
    float bj = bias[dir*G4 + j];
    const half8* wp8 = (const half8*)(whh + ((size_t)dir*32*G4 + j)*8); // +k8*G4 (half8 units)
    const half8* hp  = (const half8*)hbuf;
    __syncthreads();
    for (int s = 0; s < T_; ++s){
        int tt = dir ? (T_ - 1 - s) : s;
        size_t bt = (size_t)b*T_ + tt;
        unsigned short gxv = gx[bt*N2 + dir*G4 + j];   // issue early
        float a0 = 0.f, a1 = 0.f, a2 = 0.f, a3 = 0.f;
        #pragma unroll 4
        for (int k8 = 0; k8 < H_/8; ++k8){
            half8 wv = wp8[(size_t)k8*G4];
            half8 hv = hp[k8];                          // broadcast ds_read_b128
            a0 = fdot2(__builtin_shufflevector(wv,wv,0,1), __builtin_shufflevector(hv,hv,0,1), a0);
            a1 = fdot2(__builtin_shufflevector(wv,wv,2,3), __builtin_shufflevector(hv,hv,2,3), a1);
            a2 = fdot2(__builtin_shufflevector(wv,wv,4,5), __builtin_shufflevector(hv,hv,4,5), a2);
            a3 = fdot2(__builtin_shufflevector(wv,wv,6,7), __builtin_shufflevector(hv,hv,6,7), a3);
        }
        float gate = bf2f(gxv) + bj + ((a0 + a1) + (a2 + a3));
        gates[j] = gate;
        __syncthreads();
        if (j < H_){
            float xi = gates[j], xf = gates[H_+j], xg = gates[2*H_+j], xo = gates[3*H_+j];
            float ig = 1.f/(1.f + __expf(-xi));
            float fg = 1.f/(1.f + __expf(-xf));
            float og = 1.f/(1.f + __expf(-xo));
            float eg = __expf(2.f*xg); float gg = (eg - 1.f)/(eg + 1.f);
            c = fg*c + ig*gg;
            float ec = __expf(2.f*c); float th = (ec - 1.f)/(ec + 1.f);
            float h = og * th;
            hbuf[j] = (_Float16)h;
            store_out(&out[bt*(size_t)(2*H_) + dir*H_ + j], h);
        }
        __syncthreads();
    }
}

// ---------------- final linear: em[bt][l] = x[bt][:512] . lin_w[l] + lin_b[l] ----------------
__global__ __launch_bounds__(256) void k_linear(const float* __restrict__ x,
                                                const float* __restrict__ w,
                                                const float* __restrict__ bias,
                                                float* __restrict__ em){
    int wv = threadIdx.x >> 6, lane = threadIdx.x & 63;
    int bt = blockIdx.x*4 + wv;
    const float4* xp = (const float4*)(x + (size_t)bt*(2*H_) + lane*8);
    float4 xa = xp[0], xb = xp[1];
    #pragma unroll
    for (int l = 0; l < L_; ++l){
        const float4* wp = (const float4*)(w + (size_t)l*(2*H_) + lane*8);
        float4 wa = wp[0], wb = wp[1];
        float p = xa.x*wa.x + xa.y*wa.y + xa.z*wa.z + xa.w*wa.w
                + xb.x*wb.x + xb.y*wb.y + xb.z*wb.z + xb.w*wb.w;
        #pragma unroll
        for (int o = 32; o; o >>= 1) p += __shfl_xor(p, o);
        if (lane == 0) em[(size_t)bt*L_ + l] = p + bias[l];
    }
}

// ---------------- CRF NLL: one 64-thread block per batch row ----------------
__global__ void k_crf(const float* __restrict__ em, const int* __restrict__ labels,
                      const int* __restrict__ mask, const float* __restrict__ trans,
                      const float* __restrict__ st, const float* __restrict__ et,
                      float* __restrict__ out){
    int b = blockIdx.x, lane = threadIdx.x;
    __shared__ float tr[L_*L_];
    for (int i = lane; i < L_*L_; i += 64) tr[i] = trans[i];
    __syncthreads();
    const float* e  = em + (size_t)b*T_*L_;
    const int* lab  = labels + b*T_;
    const int* mk   = mask + b*T_;
    // gold score (lane-strided) + mask sum
    float sc = 0.f; int msum = 0;
    for (int t = lane; t < T_; t += 64){
        msum += mk[t];
        if (t >= 1)
            sc += (tr[lab[t-1]*L_ + lab[t]] + e[t*L_ + lab[t]]) * (float)mk[t];
    }
    #pragma unroll
    for (int o = 32; o; o >>= 1){ sc += __shfl_xor(sc, o); msum += __shfl_xor(msum, o); }
    // alpha recursion (lanes 0..8 hold alpha[j])
    int lj = lane < L_ ? lane : 0;
    float alpha = (lane < L_) ? (st[lj] + e[lj]) : -3.0e38f;
    for (int t = 1; t < T_; ++t){
        float v[L_]; float m = -3.0e38f;
        #pragma unroll
        for (int i = 0; i < L_; ++i){
            float ai = __shfl(alpha, i);
            v[i] = ai + tr[i*L_ + lj];
            m = fmaxf(m, v[i]);
        }
        float ssum = 0.f;
        #pragma unroll
        for (int i = 0; i < L_; ++i) ssum += __expf(v[i] - m);
        float nw = m + __logf(ssum) + e[t*L_ + lj];
        if (lane < L_ && mk[t] > 0) alpha = nw;
    }
    float av = (lane < L_) ? alpha + et[lj] : -3.0e38f;
    float m2 = av;
    #pragma unroll
    for (int o = 32; o; o >>= 1) m2 = fmaxf(m2, __shfl_xor(m2, o));
    float s2 = (lane < L_) ? __expf(av - m2) : 0.f;
    #pragma unroll
    for (int o = 32; o; o >>= 1) s2 += __shfl_xor(s2, o);
    if (lane == 0){
        float logZ = m2 + __logf(s2);
        int last = msum - 1;
        float score = sc + st[lab[0]] + e[lab[0]] + et[lab[last]];
        atomicAdd(out, (logZ - score) * (1.f/(float)B_));
    }
}

extern "C" void kernel_launch(void* const* d_in, const int* in_sizes, int n_in,
                              void* d_out, int out_size, void* d_ws, size_t ws_size,
                              hipStream_t stream){
    (void)in_sizes; (void)n_in; (void)out_size; (void)ws_size;
    const int*   ids    = (const int*)d_in[0];
    const int*   amask  = (const int*)d_in[1];
    const int*   labels = (const int*)d_in[2];
    const float* emb    = (const float*)d_in[3];
    const float* w_ih0  = (const float*)d_in[4];
    const float* w_hh0  = (const float*)d_in[5];
    const float* b0     = (const float*)d_in[6];
    const float* w_ih1  = (const float*)d_in[7];
    const float* w_hh1  = (const float*)d_in[8];
    const float* b1     = (const float*)d_in[9];
    const float* lin_w  = (const float*)d_in[10];
    const float* lin_b  = (const float*)d_in[11];
    const float* trans  = (const float*)d_in[12];
    const float* st     = (const float*)d_in[13];
    const float* et     = (const float*)d_in[14];
    float* out = (float*)d_out;

    char* ws = (char*)d_ws;
    size_t o = 0;
    auto alloc = [&](size_t bytes)->char*{
        char* p = ws + o; o = (o + bytes + 255) & ~(size_t)255; return p;
    };
    unsigned short* x0   = (unsigned short*)alloc((size_t)BT*E_*2);       // 16.8 MB
    unsigned short* wih0 = (unsigned short*)alloc((size_t)N2*E_*2);       //  1.0 MB
    unsigned short* wih1 = (unsigned short*)alloc((size_t)N2*(2*H_)*2);   //  2.1 MB
    _Float16*       whh0 = (_Float16*)alloc((size_t)2*G4*H_*2);           //  1.0 MB
    _Float16*       whh1 = (_Float16*)alloc((size_t)2*G4*H_*2);           //  1.0 MB
    unsigned short* gx   = (unsigned short*)alloc((size_t)BT*N2*2);       // 134 MB (reused L0/L1)
    unsigned short* xc1  = (unsigned short*)alloc((size_t)BT*2*H_*2);     // 33.5 MB
    float*          xc2  = (float*)alloc((size_t)BT*2*H_*4);              // 67 MB
    float*          em   = (float*)alloc((size_t)BT*L_*4 + 1024);         //  1.2 MB

    hipMemsetAsync(d_out, 0, sizeof(float), stream);

    k_pack_bf16<<<(N2*E_ + 255)/256, 256, 0, stream>>>(w_ih0, wih0, N2*E_);
    k_pack_bf16<<<(N2*2*H_ + 255)/256, 256, 0, stream>>>(w_ih1, wih1, N2*2*H_);
    k_pack_whh<<<65536/256, 256, 0, stream>>>(w_hh0, whh0);
    k_pack_whh<<<65536/256, 256, 0, stream>>>(w_hh1, whh1);
    k_embed<<<BT, E_, 0, stream>>>(ids, emb, x0);

    k_gemm<<<dim3(N2/128, BT/128), 256, 0, stream>>>(x0, wih0, gx, BT, N2, E_);
    k_rec<unsigned short><<<B_*2, G4, 0, stream>>>(gx, whh0, b0, xc1);
    k_gemm<<<dim3(N2/128, BT/128), 256, 0, stream>>>(xc1, wih1, gx, BT, N2, 2*H_);
    k_rec<float><<<B_*2, G4, 0, stream>>>(gx, whh1, b1, xc2);

    k_linear<<<BT/4, 256, 0, stream>>>(xc2, lin_w, lin_b, em);
    k_crf<<<B_, 64, 0, stream>>>(em, labels, amask, trans, st, et, out);
}

// Round 2
// 1737.245 us; speedup vs baseline: 2.7609x; 2.7609x over previous
//
#include <hip/hip_runtime.h>
#include <stdint.h>
#include <stddef.h>

#define B_ 64
#define T_ 512
#define E_ 256
#define H_ 256
#define L_ 9
#define BT (B_*T_)      // 32768
#define G4 1024         // 4*H gate rows per direction
#define N2 2048         // both directions

typedef short    bf16x8  __attribute__((ext_vector_type(8)));
typedef float    f32x4   __attribute__((ext_vector_type(4)));

__device__ __forceinline__ unsigned short f2bf(float x){
    unsigned u = __builtin_bit_cast(unsigned, x);
    u += 0x7fffu + ((u >> 16) & 1u);          // RNE
    return (unsigned short)(u >> 16);
}
__device__ __forceinline__ float bf2f(unsigned short h){
    unsigned u = ((unsigned)h) << 16;
    return __builtin_bit_cast(float, u);
}

// f32 -> OCP e4m3fn, RNE, with subnormals and 448 clamp
__device__ __forceinline__ unsigned char f32_e4m3(float x){
    unsigned b = __builtin_bit_cast(unsigned, x);
    unsigned s = b >> 31;
    float a = fabsf(x);
    if (a >= 448.f) return (unsigned char)((s<<7) | 0x7E);
    int E = (int)((b>>23)&255) - 127;
    if (E < -6) E = -6;
    int qi = (int)rintf(a * exp2f((float)(3 - E)));
    if (qi >= 16){ qi >>= 1; ++E; }
    if (qi == 0) return (unsigned char)(s<<7);
    unsigned mag = (qi >= 8) ? ((((unsigned)(E + 7)) << 3) | (unsigned)(qi - 8))
                             : (unsigned)qi;
    return (unsigned char)((s<<7) | mag);
}

__device__ __forceinline__ float sigm(float x){
    return __builtin_amdgcn_rcpf(1.f + __expf(-x));
}
__device__ __forceinline__ float tanh_(float x){
    float e = __expf(2.f*x);
    return 1.f - 2.f*__builtin_amdgcn_rcpf(e + 1.f);
}

__device__ __forceinline__ void lds_load16(void* lds, const void* g){
    __builtin_amdgcn_global_load_lds(
        (const __attribute__((address_space(1))) void*)g,
        (__attribute__((address_space(3))) void*)lds, 16, 0, 0);
}

__device__ __forceinline__ void store_out(unsigned short* p, float v){ *p = f2bf(v); }
__device__ __forceinline__ void store_out(float* p, float v){ *p = v; }

// ---------------- embedding gather ----------------
__global__ void k_embed(const int* __restrict__ ids, const float* __restrict__ emb,
                        unsigned short* __restrict__ x0){
    int bt = blockIdx.x;
    int e  = threadIdx.x;
    int id = ids[bt];
    x0[(size_t)bt*E_ + e] = f2bf(emb[(size_t)id*E_ + e]);
}

// ---------------- w_ih: permute rows into packed order + bf16 ----------------
// packed col p = dir*1024 + w*128 + uh*64 + g*16 + ul  <->  orig row = dir*1024 + g*256 + w*32 + uh*16 + ul
__global__ void k_pack_wih(const float* __restrict__ in, unsigned short* __restrict__ out, int K){
    int p = blockIdx.y;
    int k = blockIdx.x*256 + threadIdx.x;
    int dirc = p >> 10, pp = p & 1023;
    int wv = pp >> 7, rem = pp & 127;
    int uh = (rem >> 6) & 1, g = (rem >> 4) & 3, ulx = rem & 15;
    int orig = dirc*1024 + g*256 + wv*32 + uh*16 + ulx;
    out[(size_t)p*K + k] = f2bf(in[(size_t)orig*K + k]);
}

__global__ void k_pack_bias(const float* __restrict__ b, float* __restrict__ bp){
    int p = blockIdx.x*256 + threadIdx.x;   // 2048
    int dirc = p >> 10, pp = p & 1023;
    int wv = pp >> 7, rem = pp & 127;
    int uh = (rem >> 6) & 1, g = (rem >> 4) & 3, ulx = rem & 15;
    int orig = dirc*1024 + g*256 + wv*32 + uh*16 + ulx;
    bp[p] = b[orig];
}

// ---------------- w_hh -> fp8 MFMA B-fragment buffer ----------------
// layout (as 8-byte units): [dir2][w8][kk8][g4][uh2][lane64]
// element j of unit = W[dir][g*256 + w*32 + uh*16 + (lane&15)][kk*32 + (lane>>4)*8 + j]
__global__ void k_pack_wfp8(const float* __restrict__ whh, unsigned char* __restrict__ wpk){
    int idx = blockIdx.x*256 + threadIdx.x;   // 65536
    int lane = idx & 63;
    int uh   = (idx >> 6) & 1;
    int g    = (idx >> 7) & 3;
    int kk   = (idx >> 9) & 7;
    int wv   = (idx >> 12) & 7;
    int dir  = (idx >> 15) & 1;
    int ulx = lane & 15, hi4 = lane >> 4;
    int orig_row = g*256 + wv*32 + uh*16 + ulx;
    int k0 = kk*32 + hi4*8;
    const float* src = whh + ((size_t)dir*G4 + orig_row)*H_ + k0;
    unsigned long long pk = 0;
    #pragma unroll
    for (int q = 0; q < 8; ++q)
        pk |= ((unsigned long long)f32_e4m3(src[q])) << (8*q);
    ((unsigned long long*)wpk)[idx] = pk;
}

// ---------------- bf16 MFMA GEMM: C[M][N] = A[M][K]*Bm[N][K]^T + bias[N] (bf16 out) ----------------
__global__ __launch_bounds__(256) void k_gemm(const unsigned short* __restrict__ A,
                                              const unsigned short* __restrict__ Bm,
                                              const float* __restrict__ bias,
                                              unsigned short* __restrict__ C,
                                              int M, int N, int K){
    __shared__ unsigned short As[128*32];
    __shared__ unsigned short Bs[128*32];
    int tid = threadIdx.x, lane = tid & 63, w = tid >> 6;
    int wm = w >> 1, wn = w & 1;
    int tileM = blockIdx.y * 128, tileN = blockIdx.x * 128;
    f32x4 acc[4][4] = {};
    const char* Ab = (const char*)A;
    const char* Bb = (const char*)Bm;
    for (int k0 = 0; k0 < K; k0 += 32){
        #pragma unroll
        for (int i = 0; i < 2; ++i){
            int off = (w*2 + i)*1024 + lane*16;
            int row = off >> 6, colb = off & 63;
            lds_load16((char*)As + (w*2+i)*1024,
                       Ab + ((size_t)(tileM + row)*K + k0)*2 + colb);
            lds_load16((char*)Bs + (w*2+i)*1024,
                       Bb + ((size_t)(tileN + row)*K + k0)*2 + colb);
        }
        __syncthreads();
        int kloc = (lane >> 4) * 8;
        bf16x8 af[4], bfv[4];
        #pragma unroll
        for (int mf = 0; mf < 4; ++mf)
            af[mf] = *(const bf16x8*)&As[(wm*64 + mf*16 + (lane & 15))*32 + kloc];
        #pragma unroll
        for (int nf = 0; nf < 4; ++nf)
            bfv[nf] = *(const bf16x8*)&Bs[(wn*64 + nf*16 + (lane & 15))*32 + kloc];
        #pragma unroll
        for (int mf = 0; mf < 4; ++mf)
            #pragma unroll
            for (int nf = 0; nf < 4; ++nf)
                acc[mf][nf] = __builtin_amdgcn_mfma_f32_16x16x32_bf16(
                                  af[mf], bfv[nf], acc[mf][nf], 0, 0, 0);
        __syncthreads();
    }
    #pragma unroll
    for (int mf = 0; mf < 4; ++mf){
        #pragma unroll
        for (int nf = 0; nf < 4; ++nf){
            int row0 = tileM + wm*64 + mf*16 + (lane >> 4)*4;
            int col  = tileN + wn*64 + nf*16 + (lane & 15);
            float bv = bias[col];
            #pragma unroll
            for (int r = 0; r < 4; ++r)
                C[(size_t)(row0 + r)*N + col] = f2bf(acc[mf][nf][r] + bv);
        }
    }
}

// ---------------- LSTM recurrence, fp8 MFMA, weights register-resident ----------------
// grid = 32 blocks: blk = bg*2's... blk&1 = dir, blk>>1 = bg(0..15); block = 512 thr (8 waves).
// Wave w owns units [w*32, w*32+32) x 4 gates = 128 gate rows. M=4 batches = bg*4 + (lane>>4).
// gx: [BT][2048] packed cols, bias pre-added. wpk: fp8 frags. out: [BT][512].
template<typename OutT>
__global__ __launch_bounds__(512, 2)
void k_rec_mfma(const unsigned short* __restrict__ gx,
                const unsigned char* __restrict__ wpk,
                OutT* __restrict__ out){
    int blk = blockIdx.x;
    int dir = blk & 1, bg = blk >> 1;
    int tid = threadIdx.x, lane = tid & 63, w = tid >> 6;
    int ul = lane & 15, hi4 = lane >> 4;
    int batch = bg*4 + hi4;

    // h state: fp8, [buf2][kb32][Arow16][8B]; batch bl lives at Arow bl*4
    __shared__ __align__(16) unsigned char hlds[2][32][16][8];
    {
        unsigned long long* hz = (unsigned long long*)hlds;
        for (int i = tid; i < 1024; i += 512) hz[i] = 0ull;
    }

    // register-resident W fragments (fully static-indexed)
    long wf[8][4][2];
    {
        const long* wb = (const long*)wpk;
        #pragma unroll
        for (int kk = 0; kk < 8; ++kk)
            #pragma unroll
            for (int g = 0; g < 4; ++g)
                #pragma unroll
                for (int uh = 0; uh < 2; ++uh)
                    wf[kk][g][uh] = wb[(((((size_t)dir*8 + w)*8 + kk)*4 + g)*2 + uh)*64 + lane];
    }
    __syncthreads();

    const unsigned short* gp = gx + (size_t)(batch*T_ + (dir ? T_-1 : 0))*N2
                                  + dir*1024 + w*128 + ul;
    ptrdiff_t dstep = dir ? -(ptrdiff_t)N2 : (ptrdiff_t)N2;

    unsigned short gxr[8];
    #pragma unroll
    for (int uh = 0; uh < 2; ++uh)
        #pragma unroll
        for (int g = 0; g < 4; ++g)
            gxr[uh*4+g] = gp[uh*64 + g*16];

    float c0 = 0.f, c1 = 0.f;
    int u0 = w*32 + ul, u1 = u0 + 16;
    OutT* ob = out + (size_t)batch*T_*512 + dir*256;

    for (int s = 0; s < T_; ++s){
        int buf = s & 1;
        // init acc from gx (lane's batch sits at D-row hi4*4 -> reg 0)
        f32x4 acc[4][2];
        #pragma unroll
        for (int g = 0; g < 4; ++g)
            #pragma unroll
            for (int uh = 0; uh < 2; ++uh)
                acc[g][uh] = (f32x4){ bf2f(gxr[uh*4+g]), 0.f, 0.f, 0.f };

        // prefetch next step's gx (harmlessly reads adjacent ws at the ends)
        gp += dstep;
        unsigned short gxn[8];
        #pragma unroll
        for (int uh = 0; uh < 2; ++uh)
            #pragma unroll
            for (int g = 0; g < 4; ++g)
                gxn[uh*4+g] = gp[uh*64 + g*16];

        // MFMA: gates += h @ W^T
        const long* hrow = (const long*)&hlds[buf][0][0][0];
        #pragma unroll
        for (int kk = 0; kk < 8; ++kk){
            long af = hrow[(kk*4 + hi4)*16 + ul];
            #pragma unroll
            for (int g = 0; g < 4; ++g)
                #pragma unroll
                for (int uh = 0; uh < 2; ++uh)
                    acc[g][uh] = __builtin_amdgcn_mfma_f32_16x16x32_fp8_fp8(
                                     af, wf[kk][g][uh], acc[g][uh], 0, 0, 0);
        }

        // cell updates: 2 cells/lane (units u0, u1; batch = bg*4+hi4)
        int tt = dir ? (T_-1-s) : s;
        float h0, h1;
        {
            float xi = acc[0][0][0], xf = acc[1][0][0], xg = acc[2][0][0], xo = acc[3][0][0];
            c0 = sigm(xf)*c0 + sigm(xi)*tanh_(xg);
            h0 = sigm(xo)*tanh_(c0);
        }
        {
            float xi = acc[0][1][0], xf = acc[1][1][0], xg = acc[2][1][0], xo = acc[3][1][0];
            c1 = sigm(xf)*c1 + sigm(xi)*tanh_(xg);
            h1 = sigm(xo)*tanh_(c1);
        }

        unsigned char hb0, hb1;
#if __has_builtin(__builtin_amdgcn_cvt_pk_fp8_f32)
        {
            int pk = __builtin_amdgcn_cvt_pk_fp8_f32(h0, h1, 0, false);
            hb0 = (unsigned char)(pk & 0xff);
            hb1 = (unsigned char)((pk >> 8) & 0xff);
        }
#else
        hb0 = f32_e4m3(h0); hb1 = f32_e4m3(h1);
#endif
        hlds[buf^1][u0>>3][hi4*4][u0&7] = hb0;
        hlds[buf^1][u1>>3][hi4*4][u1&7] = hb1;

        store_out(&ob[(size_t)tt*512 + u0], h0);
        store_out(&ob[(size_t)tt*512 + u1], h1);

        #pragma unroll
        for (int i = 0; i < 8; ++i) gxr[i] = gxn[i];
        __syncthreads();
    }
}

// ---------------- final linear ----------------
__global__ __launch_bounds__(256) void k_linear(const float* __restrict__ x,
                                                const float* __restrict__ w,
                                                const float* __restrict__ bias,
                                                float* __restrict__ em){
    int wv = threadIdx.x >> 6, lane = threadIdx.x & 63;
    int bt = blockIdx.x*4 + wv;
    const float4* xp = (const float4*)(x + (size_t)bt*(2*H_) + lane*8);
    float4 xa = xp[0], xb = xp[1];
    #pragma unroll
    for (int l = 0; l < L_; ++l){
        const float4* wp = (const float4*)(w + (size_t)l*(2*H_) + lane*8);
        float4 wa = wp[0], wb = wp[1];
        float p = xa.x*wa.x + xa.y*wa.y + xa.z*wa.z + xa.w*wa.w
                + xb.x*wb.x + xb.y*wb.y + xb.z*wb.z + xb.w*wb.w;
        #pragma unroll
        for (int o = 32; o; o >>= 1) p += __shfl_xor(p, o);
        if (lane == 0) em[(size_t)bt*L_ + l] = p + bias[l];
    }
}

// ---------------- CRF NLL ----------------
__global__ void k_crf(const float* __restrict__ em, const int* __restrict__ labels,
                      const int* __restrict__ mask, const float* __restrict__ trans,
                      const float* __restrict__ st, const float* __restrict__ et,
                      float* __restrict__ out){
    int b = blockIdx.x, lane = threadIdx.x;
    __shared__ float tr[L_*L_];
    for (int i = lane; i < L_*L_; i += 64) tr[i] = trans[i];
    __syncthreads();
    const float* e  = em + (size_t)b*T_*L_;
    const int* lab  = labels + b*T_;
    const int* mk   = mask + b*T_;
    float sc = 0.f; int msum = 0;
    for (int t = lane; t < T_; t += 64){
        msum += mk[t];
        if (t >= 1)
            sc += (tr[lab[t-1]*L_ + lab[t]] + e[t*L_ + lab[t]]) * (float)mk[t];
    }
    #pragma unroll
    for (int o = 32; o; o >>= 1){ sc += __shfl_xor(sc, o); msum += __shfl_xor(msum, o); }
    int lj = lane < L_ ? lane : 0;
    float alpha = (lane < L_) ? (st[lj] + e[lj]) : -3.0e38f;
    for (int t = 1; t < T_; ++t){
        float v[L_]; float m = -3.0e38f;
        #pragma unroll
        for (int i = 0; i < L_; ++i){
            float ai = __shfl(alpha, i);
            v[i] = ai + tr[i*L_ + lj];
            m = fmaxf(m, v[i]);
        }
        float ssum = 0.f;
        #pragma unroll
        for (int i = 0; i < L_; ++i) ssum += __expf(v[i] - m);
        float nw = m + __logf(ssum) + e[t*L_ + lj];
        if (lane < L_ && mk[t] > 0) alpha = nw;
    }
    float av = (lane < L_) ? alpha + et[lj] : -3.0e38f;
    float m2 = av;
    #pragma unroll
    for (int o = 32; o; o >>= 1) m2 = fmaxf(m2, __shfl_xor(m2, o));
    float s2 = (lane < L_) ? __expf(av - m2) : 0.f;
    #pragma unroll
    for (int o = 32; o; o >>= 1) s2 += __shfl_xor(s2, o);
    if (lane == 0){
        float logZ = m2 + __logf(s2);
        int last = msum - 1;
        float score = sc + st[lab[0]] + e[lab[0]] + et[lab[last]];
        atomicAdd(out, (logZ - score) * (1.f/(float)B_));
    }
}

extern "C" void kernel_launch(void* const* d_in, const int* in_sizes, int n_in,
                              void* d_out, int out_size, void* d_ws, size_t ws_size,
                              hipStream_t stream){
    (void)in_sizes; (void)n_in; (void)out_size; (void)ws_size;
    const int*   ids    = (const int*)d_in[0];
    const int*   amask  = (const int*)d_in[1];
    const int*   labels = (const int*)d_in[2];
    const float* emb    = (const float*)d_in[3];
    const float* w_ih0  = (const float*)d_in[4];
    const float* w_hh0  = (const float*)d_in[5];
    const float* b0     = (const float*)d_in[6];
    const float* w_ih1  = (const float*)d_in[7];
    const float* w_hh1  = (const float*)d_in[8];
    const float* b1     = (const float*)d_in[9];
    const float* lin_w  = (const float*)d_in[10];
    const float* lin_b  = (const float*)d_in[11];
    const float* trans  = (const float*)d_in[12];
    const float* st     = (const float*)d_in[13];
    const float* et     = (const float*)d_in[14];
    float* out = (float*)d_out;

    char* ws = (char*)d_ws;
    size_t o = 0;
    auto alloc = [&](size_t bytes)->char*{
        char* p = ws + o; o = (o + bytes + 255) & ~(size_t)255; return p;
    };
    unsigned short* x0    = (unsigned short*)alloc((size_t)BT*E_*2);
    unsigned short* wih0p = (unsigned short*)alloc((size_t)N2*E_*2);
    unsigned short* wih1p = (unsigned short*)alloc((size_t)N2*512*2);
    unsigned char*  wpk0  = (unsigned char*)alloc(65536*8);
    unsigned char*  wpk1  = (unsigned char*)alloc(65536*8);
    float*          bp0   = (float*)alloc(N2*4);
    float*          bp1   = (float*)alloc(N2*4);
    unsigned short* gx    = (unsigned short*)alloc((size_t)BT*N2*2);
    unsigned short* xc1   = (unsigned short*)alloc((size_t)BT*512*2);
    float*          xc2   = (float*)alloc((size_t)BT*512*4);
    float*          em    = (float*)alloc((size_t)BT*L_*4 + 1024);

    hipMemsetAsync(d_out, 0, sizeof(float), stream);

    k_pack_wih<<<dim3(E_/256, N2), 256, 0, stream>>>(w_ih0, wih0p, E_);
    k_pack_wih<<<dim3(512/256, N2), 256, 0, stream>>>(w_ih1, wih1p, 512);
    k_pack_bias<<<N2/256, 256, 0, stream>>>(b0, bp0);
    k_pack_bias<<<N2/256, 256, 0, stream>>>(b1, bp1);
    k_pack_wfp8<<<65536/256, 256, 0, stream>>>(w_hh0, wpk0);
    k_pack_wfp8<<<65536/256, 256, 0, stream>>>(w_hh1, wpk1);
    k_embed<<<BT, E_, 0, stream>>>(ids, emb, x0);

    k_gemm<<<dim3(N2/128, BT/128), 256, 0, stream>>>(x0, wih0p, bp0, gx, BT, N2, E_);
    k_rec_mfma<unsigned short><<<32, 512, 0, stream>>>(gx, wpk0, xc1);
    k_gemm<<<dim3(N2/128, BT/128), 256, 0, stream>>>(xc1, wih1p, bp1, gx, BT, N2, 512);
    k_rec_mfma<float><<<32, 512, 0, stream>>>(gx, wpk1, xc2);

    k_linear<<<BT/4, 256, 0, stream>>>(xc2, lin_w, lin_b, em);
    k_crf<<<B_, 64, 0, stream>>>(em, labels, amask, trans, st, et, out);
}

// Round 3
// 1358.487 us; speedup vs baseline: 3.5306x; 1.2788x over previous
//
#include <hip/hip_runtime.h>
#include <stdint.h>
#include <stddef.h>

#define B_ 64
#define T_ 512
#define E_ 256
#define H_ 256
#define L_ 9
#define BT (B_*T_)      // 32768
#define G4 1024         // 4*H gate rows per direction
#define N2 2048         // both directions

typedef short    bf16x8  __attribute__((ext_vector_type(8)));
typedef float    f32x4   __attribute__((ext_vector_type(4)));
typedef int      i32x8   __attribute__((ext_vector_type(8)));

__device__ __forceinline__ unsigned short f2bf(float x){
    unsigned u = __builtin_bit_cast(unsigned, x);
    u += 0x7fffu + ((u >> 16) & 1u);          // RNE
    return (unsigned short)(u >> 16);
}
__device__ __forceinline__ float bf2f(unsigned short h){
    unsigned u = ((unsigned)h) << 16;
    return __builtin_bit_cast(float, u);
}

// f32 -> OCP e4m3fn, RNE, with subnormals and 448 clamp
__device__ __forceinline__ unsigned char f32_e4m3(float x){
    unsigned b = __builtin_bit_cast(unsigned, x);
    unsigned s = b >> 31;
    float a = fabsf(x);
    if (a >= 448.f) return (unsigned char)((s<<7) | 0x7E);
    int E = (int)((b>>23)&255) - 127;
    if (E < -6) E = -6;
    int qi = (int)rintf(a * exp2f((float)(3 - E)));
    if (qi >= 16){ qi >>= 1; ++E; }
    if (qi == 0) return (unsigned char)(s<<7);
    unsigned mag = (qi >= 8) ? ((((unsigned)(E + 7)) << 3) | (unsigned)(qi - 8))
                             : (unsigned)qi;
    return (unsigned char)((s<<7) | mag);
}

__device__ __forceinline__ float sigm(float x){
    return __builtin_amdgcn_rcpf(1.f + __expf(-x));
}
__device__ __forceinline__ float tanh_(float x){
    float e = __expf(2.f*x);
    return 1.f - 2.f*__builtin_amdgcn_rcpf(e + 1.f);
}

__device__ __forceinline__ void lds_load16(void* lds, const void* g){
    __builtin_amdgcn_global_load_lds(
        (const __attribute__((address_space(1))) void*)g,
        (__attribute__((address_space(3))) void*)lds, 16, 0, 0);
}

__device__ __forceinline__ void store_out(unsigned short* p, float v){ *p = f2bf(v); }
__device__ __forceinline__ void store_out(float* p, float v){ *p = v; }

// ---------------- embedding gather ----------------
__global__ void k_embed(const int* __restrict__ ids, const float* __restrict__ emb,
                        unsigned short* __restrict__ x0){
    int bt = blockIdx.x;
    int e  = threadIdx.x;
    int id = ids[bt];
    x0[(size_t)bt*E_ + e] = f2bf(emb[(size_t)id*E_ + e]);
}

// ---------------- w_ih: permute rows into packed order + bf16 ----------------
// packed col p = dir*1024 + w*128 + uh*64 + g*16 + ul  <->  orig row = dir*1024 + g*256 + w*32 + uh*16 + ul
__global__ void k_pack_wih(const float* __restrict__ in, unsigned short* __restrict__ out, int K){
    int p = blockIdx.y;
    int k = blockIdx.x*256 + threadIdx.x;
    int dirc = p >> 10, pp = p & 1023;
    int wv = pp >> 7, rem = pp & 127;
    int uh = (rem >> 6) & 1, g = (rem >> 4) & 3, ulx = rem & 15;
    int orig = dirc*1024 + g*256 + wv*32 + uh*16 + ulx;
    out[(size_t)p*K + k] = f2bf(in[(size_t)orig*K + k]);
}

__global__ void k_pack_bias(const float* __restrict__ b, float* __restrict__ bp){
    int p = blockIdx.x*256 + threadIdx.x;   // 2048
    int dirc = p >> 10, pp = p & 1023;
    int wv = pp >> 7, rem = pp & 127;
    int uh = (rem >> 6) & 1, g = (rem >> 4) & 3, ulx = rem & 15;
    int orig = dirc*1024 + g*256 + wv*32 + uh*16 + ulx;
    bp[p] = b[orig];
}

// ---------------- w_hh -> fp8 MFMA B-fragment buffer (K=128 f8f6f4 frags) ----------------
// layout (32-byte units): [dir2][w8][kt2][g4][uh2][lane64]
// byte j of unit = W[dir][g*256 + w*32 + uh*16 + (lane&15)][kt*128 + (lane>>4)*32 + j]
__global__ void k_pack_wfp8(const float* __restrict__ whh, unsigned char* __restrict__ wpk){
    int idx = blockIdx.x*256 + threadIdx.x;   // 16384 total
    int lane = idx & 63;
    int uh   = (idx >> 6) & 1;
    int g    = (idx >> 7) & 3;
    int kt   = (idx >> 9) & 1;
    int wv   = (idx >> 10) & 7;
    int dir  = (idx >> 13) & 1;
    int ulx = lane & 15, hi4 = lane >> 4;
    int row = g*256 + wv*32 + uh*16 + ulx;
    int k0 = kt*128 + hi4*32;
    const float* src = whh + ((size_t)dir*G4 + row)*H_ + k0;
    unsigned char* dst = wpk + (size_t)idx*32;
    #pragma unroll
    for (int q = 0; q < 32; ++q) dst[q] = f32_e4m3(src[q]);
}

// ---------------- bf16 MFMA GEMM: C[M][N] = A[M][K]*Bm[N][K]^T + bias[N] (bf16 out) ----------------
__global__ __launch_bounds__(256) void k_gemm(const unsigned short* __restrict__ A,
                                              const unsigned short* __restrict__ Bm,
                                              const float* __restrict__ bias,
                                              unsigned short* __restrict__ C,
                                              int M, int N, int K){
    __shared__ unsigned short As[128*32];
    __shared__ unsigned short Bs[128*32];
    int tid = threadIdx.x, lane = tid & 63, w = tid >> 6;
    int wm = w >> 1, wn = w & 1;
    int tileM = blockIdx.y * 128, tileN = blockIdx.x * 128;
    f32x4 acc[4][4] = {};
    const char* Ab = (const char*)A;
    const char* Bb = (const char*)Bm;
    for (int k0 = 0; k0 < K; k0 += 32){
        #pragma unroll
        for (int i = 0; i < 2; ++i){
            int off = (w*2 + i)*1024 + lane*16;
            int row = off >> 6, colb = off & 63;
            lds_load16((char*)As + (w*2+i)*1024,
                       Ab + ((size_t)(tileM + row)*K + k0)*2 + colb);
            lds_load16((char*)Bs + (w*2+i)*1024,
                       Bb + ((size_t)(tileN + row)*K + k0)*2 + colb);
        }
        __syncthreads();
        int kloc = (lane >> 4) * 8;
        bf16x8 af[4], bfv[4];
        #pragma unroll
        for (int mf = 0; mf < 4; ++mf)
            af[mf] = *(const bf16x8*)&As[(wm*64 + mf*16 + (lane & 15))*32 + kloc];
        #pragma unroll
        for (int nf = 0; nf < 4; ++nf)
            bfv[nf] = *(const bf16x8*)&Bs[(wn*64 + nf*16 + (lane & 15))*32 + kloc];
        #pragma unroll
        for (int mf = 0; mf < 4; ++mf)
            #pragma unroll
            for (int nf = 0; nf < 4; ++nf)
                acc[mf][nf] = __builtin_amdgcn_mfma_f32_16x16x32_bf16(
                                  af[mf], bfv[nf], acc[mf][nf], 0, 0, 0);
        __syncthreads();
    }
    #pragma unroll
    for (int mf = 0; mf < 4; ++mf){
        #pragma unroll
        for (int nf = 0; nf < 4; ++nf){
            int row0 = tileM + wm*64 + mf*16 + (lane >> 4)*4;
            int col  = tileN + wn*64 + nf*16 + (lane & 15);
            float bv = bias[col];
            #pragma unroll
            for (int r = 0; r < 4; ++r)
                C[(size_t)(row0 + r)*N + col] = f2bf(acc[mf][nf][r] + bv);
        }
    }
}

// ---------------- LSTM recurrence, MX-scaled fp8 MFMA (K=128), weights register-resident ----------------
// grid = 32 blocks: blk&1 = dir, blk>>1 = bg(0..15); block = 512 thr (8 waves).
// Wave w owns units [w*32, w*32+32) x 4 gates. Batches = bg*4 + (lane>>4) at A/D row (lane>>4)*4.
// gx: [BT][2048] packed cols, bias pre-added. wpk: fp8 K=128 frags. out: [BT][512].
template<typename OutT>
__global__ __launch_bounds__(512, 2)
void k_rec_mfma(const unsigned short* __restrict__ gx,
                const unsigned char* __restrict__ wpk,
                OutT* __restrict__ out){
    int blk = blockIdx.x;
    int dir = blk & 1, bg = blk >> 1;
    int tid = threadIdx.x, lane = tid & 63, w = tid >> 6;
    int ul = lane & 15, hi4 = lane >> 4;
    int batch = bg*4 + hi4;

    // h state: fp8, [buf2][kb32][Arow16][8B]; batch q lives at Arow q*4; h[unit u] at kb=u>>3, byte=u&7
    __shared__ __align__(16) unsigned char hlds[2][32][16][8];
    {
        unsigned long long* hz = (unsigned long long*)hlds;
        for (int i = tid; i < 1024; i += 512) hz[i] = 0ull;
    }

    // register-resident W fragments: [kt2][g4][uh2], 32 B/lane each
    i32x8 wf[2][4][2];
    {
        const i32x8* wb = (const i32x8*)wpk;
        #pragma unroll
        for (int kt = 0; kt < 2; ++kt)
            #pragma unroll
            for (int g = 0; g < 4; ++g)
                #pragma unroll
                for (int uh = 0; uh < 2; ++uh)
                    wf[kt][g][uh] = wb[((((size_t)(dir*8 + w)*2 + kt)*4 + g)*2 + uh)*64 + lane];
    }
    __syncthreads();

    const unsigned short* gp = gx + (size_t)(batch*T_ + (dir ? T_-1 : 0))*N2
                                  + dir*1024 + w*128 + ul;
    ptrdiff_t dstep = dir ? -(ptrdiff_t)N2 : (ptrdiff_t)N2;

    unsigned short gxr[8];
    #pragma unroll
    for (int uh = 0; uh < 2; ++uh)
        #pragma unroll
        for (int g = 0; g < 4; ++g)
            gxr[uh*4+g] = gp[uh*64 + g*16];

    float c0 = 0.f, c1 = 0.f;
    int u0 = w*32 + ul, u1 = u0 + 16;
    OutT* ob = out + (size_t)batch*T_*512 + dir*256;

    for (int s = 0; s < T_; ++s){
        int buf = s & 1;
        f32x4 acc[4][2];
        #pragma unroll
        for (int g = 0; g < 4; ++g)
            #pragma unroll
            for (int uh = 0; uh < 2; ++uh)
                acc[g][uh] = (f32x4){ bf2f(gxr[uh*4+g]), 0.f, 0.f, 0.f };

        // prefetch next step's gx
        gp += dstep;
        unsigned short gxn[8];
        #pragma unroll
        for (int uh = 0; uh < 2; ++uh)
            #pragma unroll
            for (int g = 0; g < 4; ++g)
                gxn[uh*4+g] = gp[uh*64 + g*16];

        // MFMA: gates += h @ W^T   (2 K-tiles of 128)
        const unsigned long long* hrow = (const unsigned long long*)&hlds[buf][0][0][0];
        #pragma unroll
        for (int kt = 0; kt < 2; ++kt){
            // A frag: row = ul, k = kt*128 + hi4*32 + j  ->  kb = kt*16 + hi4*4 + (j>>3)
            unsigned long long a0 = hrow[(kt*16 + hi4*4 + 0)*16 + ul];
            unsigned long long a1 = hrow[(kt*16 + hi4*4 + 1)*16 + ul];
            unsigned long long a2 = hrow[(kt*16 + hi4*4 + 2)*16 + ul];
            unsigned long long a3 = hrow[(kt*16 + hi4*4 + 3)*16 + ul];
            i32x8 af = (i32x8){ (int)a0, (int)(a0>>32), (int)a1, (int)(a1>>32),
                                (int)a2, (int)(a2>>32), (int)a3, (int)(a3>>32) };
            #pragma unroll
            for (int g = 0; g < 4; ++g)
                #pragma unroll
                for (int uh = 0; uh < 2; ++uh)
                    acc[g][uh] = __builtin_amdgcn_mfma_scale_f32_16x16x128_f8f6f4(
                                     af, wf[kt][g][uh], acc[g][uh],
                                     0, 0,               // cbsz=fp8(A), blgp=fp8(B)
                                     0, 0x7f7f7f7f,      // A scales = 1.0 (e8m0)
                                     0, 0x7f7f7f7f);     // B scales = 1.0
        }

        // cell updates: 2 cells/lane (units u0, u1)
        int tt = dir ? (T_-1-s) : s;
        float h0, h1;
        {
            float xi = acc[0][0][0], xf = acc[1][0][0], xg = acc[2][0][0], xo = acc[3][0][0];
            c0 = sigm(xf)*c0 + sigm(xi)*tanh_(xg);
            h0 = sigm(xo)*tanh_(c0);
        }
        {
            float xi = acc[0][1][0], xf = acc[1][1][0], xg = acc[2][1][0], xo = acc[3][1][0];
            c1 = sigm(xf)*c1 + sigm(xi)*tanh_(xg);
            h1 = sigm(xo)*tanh_(c1);
        }

        unsigned char hb0, hb1;
#if __has_builtin(__builtin_amdgcn_cvt_pk_fp8_f32)
        {
            int pk = __builtin_amdgcn_cvt_pk_fp8_f32(h0, h1, 0, false);
            hb0 = (unsigned char)(pk & 0xff);
            hb1 = (unsigned char)((pk >> 8) & 0xff);
        }
#else
        hb0 = f32_e4m3(h0); hb1 = f32_e4m3(h1);
#endif
        hlds[buf^1][u0>>3][hi4*4][u0&7] = hb0;
        hlds[buf^1][u1>>3][hi4*4][u1&7] = hb1;

        store_out(&ob[(size_t)tt*512 + u0], h0);
        store_out(&ob[(size_t)tt*512 + u1], h1);

        #pragma unroll
        for (int i = 0; i < 8; ++i) gxr[i] = gxn[i];
        __syncthreads();
    }
}

// ---------------- final linear ----------------
__global__ __launch_bounds__(256) void k_linear(const float* __restrict__ x,
                                                const float* __restrict__ w,
                                                const float* __restrict__ bias,
                                                float* __restrict__ em){
    int wv = threadIdx.x >> 6, lane = threadIdx.x & 63;
    int bt = blockIdx.x*4 + wv;
    const float4* xp = (const float4*)(x + (size_t)bt*(2*H_) + lane*8);
    float4 xa = xp[0], xb = xp[1];
    #pragma unroll
    for (int l = 0; l < L_; ++l){
        const float4* wp = (const float4*)(w + (size_t)l*(2*H_) + lane*8);
        float4 wa = wp[0], wb = wp[1];
        float p = xa.x*wa.x + xa.y*wa.y + xa.z*wa.z + xa.w*wa.w
                + xb.x*wb.x + xb.y*wb.y + xb.z*wb.z + xb.w*wb.w;
        #pragma unroll
        for (int o = 32; o; o >>= 1) p += __shfl_xor(p, o);
        if (lane == 0) em[(size_t)bt*L_ + l] = p + bias[l];
    }
}

// ---------------- CRF NLL ----------------
__global__ void k_crf(const float* __restrict__ em, const int* __restrict__ labels,
                      const int* __restrict__ mask, const float* __restrict__ trans,
                      const float* __restrict__ st, const float* __restrict__ et,
                      float* __restrict__ out){
    int b = blockIdx.x, lane = threadIdx.x;
    __shared__ float tr[L_*L_];
    for (int i = lane; i < L_*L_; i += 64) tr[i] = trans[i];
    __syncthreads();
    const float* e  = em + (size_t)b*T_*L_;
    const int* lab  = labels + b*T_;
    const int* mk   = mask + b*T_;
    float sc = 0.f; int msum = 0;
    for (int t = lane; t < T_; t += 64){
        msum += mk[t];
        if (t >= 1)
            sc += (tr[lab[t-1]*L_ + lab[t]] + e[t*L_ + lab[t]]) * (float)mk[t];
    }
    #pragma unroll
    for (int o = 32; o; o >>= 1){ sc += __shfl_xor(sc, o); msum += __shfl_xor(msum, o); }
    int lj = lane < L_ ? lane : 0;
    float alpha = (lane < L_) ? (st[lj] + e[lj]) : -3.0e38f;
    for (int t = 1; t < T_; ++t){
        float v[L_]; float m = -3.0e38f;
        #pragma unroll
        for (int i = 0; i < L_; ++i){
            float ai = __shfl(alpha, i);
            v[i] = ai + tr[i*L_ + lj];
            m = fmaxf(m, v[i]);
        }
        float ssum = 0.f;
        #pragma unroll
        for (int i = 0; i < L_; ++i) ssum += __expf(v[i] - m);
        float nw = m + __logf(ssum) + e[t*L_ + lj];
        if (lane < L_ && mk[t] > 0) alpha = nw;
    }
    float av = (lane < L_) ? alpha + et[lj] : -3.0e38f;
    float m2 = av;
    #pragma unroll
    for (int o = 32; o; o >>= 1) m2 = fmaxf(m2, __shfl_xor(m2, o));
    float s2 = (lane < L_) ? __expf(av - m2) : 0.f;
    #pragma unroll
    for (int o = 32; o; o >>= 1) s2 += __shfl_xor(s2, o);
    if (lane == 0){
        float logZ = m2 + __logf(s2);
        int last = msum - 1;
        float score = sc + st[lab[0]] + e[lab[0]] + et[lab[last]];
        atomicAdd(out, (logZ - score) * (1.f/(float)B_));
    }
}

extern "C" void kernel_launch(void* const* d_in, const int* in_sizes, int n_in,
                              void* d_out, int out_size, void* d_ws, size_t ws_size,
                              hipStream_t stream){
    (void)in_sizes; (void)n_in; (void)out_size; (void)ws_size;
    const int*   ids    = (const int*)d_in[0];
    const int*   amask  = (const int*)d_in[1];
    const int*   labels = (const int*)d_in[2];
    const float* emb    = (const float*)d_in[3];
    const float* w_ih0  = (const float*)d_in[4];
    const float* w_hh0  = (const float*)d_in[5];
    const float* b0     = (const float*)d_in[6];
    const float* w_ih1  = (const float*)d_in[7];
    const float* w_hh1  = (const float*)d_in[8];
    const float* b1     = (const float*)d_in[9];
    const float* lin_w  = (const float*)d_in[10];
    const float* lin_b  = (const float*)d_in[11];
    const float* trans  = (const float*)d_in[12];
    const float* st     = (const float*)d_in[13];
    const float* et     = (const float*)d_in[14];
    float* out = (float*)d_out;

    char* ws = (char*)d_ws;
    size_t o = 0;
    auto alloc = [&](size_t bytes)->char*{
        char* p = ws + o; o = (o + bytes + 255) & ~(size_t)255; return p;
    };
    unsigned short* x0    = (unsigned short*)alloc((size_t)BT*E_*2);
    unsigned short* wih0p = (unsigned short*)alloc((size_t)N2*E_*2);
    unsigned short* wih1p = (unsigned short*)alloc((size_t)N2*512*2);
    unsigned char*  wpk0  = (unsigned char*)alloc(16384*32);
    unsigned char*  wpk1  = (unsigned char*)alloc(16384*32);
    float*          bp0   = (float*)alloc(N2*4);
    float*          bp1   = (float*)alloc(N2*4);
    unsigned short* gx    = (unsigned short*)alloc((size_t)BT*N2*2);
    unsigned short* xc1   = (unsigned short*)alloc((size_t)BT*512*2);
    float*          xc2   = (float*)alloc((size_t)BT*512*4);
    float*          em    = (float*)alloc((size_t)BT*L_*4 + 1024);

    hipMemsetAsync(d_out, 0, sizeof(float), stream);

    k_pack_wih<<<dim3(E_/256, N2), 256, 0, stream>>>(w_ih0, wih0p, E_);
    k_pack_wih<<<dim3(512/256, N2), 256, 0, stream>>>(w_ih1, wih1p, 512);
    k_pack_bias<<<N2/256, 256, 0, stream>>>(b0, bp0);
    k_pack_bias<<<N2/256, 256, 0, stream>>>(b1, bp1);
    k_pack_wfp8<<<16384/256, 256, 0, stream>>>(w_hh0, wpk0);
    k_pack_wfp8<<<16384/256, 256, 0, stream>>>(w_hh1, wpk1);
    k_embed<<<BT, E_, 0, stream>>>(ids, emb, x0);

    k_gemm<<<dim3(N2/128, BT/128), 256, 0, stream>>>(x0, wih0p, bp0, gx, BT, N2, E_);
    k_rec_mfma<unsigned short><<<32, 512, 0, stream>>>(gx, wpk0, xc1);
    k_gemm<<<dim3(N2/128, BT/128), 256, 0, stream>>>(xc1, wih1p, bp1, gx, BT, N2, 512);
    k_rec_mfma<float><<<32, 512, 0, stream>>>(gx, wpk1, xc2);

    k_linear<<<BT/4, 256, 0, stream>>>(xc2, lin_w, lin_b, em);
    k_crf<<<B_, 64, 0, stream>>>(em, labels, amask, trans, st, et, out);
}

// Round 4
// 1316.598 us; speedup vs baseline: 3.6430x; 1.0318x over previous
//
#include <hip/hip_runtime.h>
#include <stdint.h>
#include <stddef.h>

#define B_ 64
#define T_ 512
#define E_ 256
#define H_ 256
#define L_ 9
#define BT (B_*T_)      // 32768
#define G4 1024         // 4*H gate rows per direction
#define N2 2048         // both directions

typedef short    bf16x8  __attribute__((ext_vector_type(8)));
typedef float    f32x4   __attribute__((ext_vector_type(4)));
typedef int      i32x4   __attribute__((ext_vector_type(4)));
typedef int      i32x8   __attribute__((ext_vector_type(8)));

__device__ __forceinline__ unsigned short f2bf(float x){
    unsigned u = __builtin_bit_cast(unsigned, x);
    u += 0x7fffu + ((u >> 16) & 1u);          // RNE
    return (unsigned short)(u >> 16);
}
__device__ __forceinline__ float bf2f(unsigned short h){
    unsigned u = ((unsigned)h) << 16;
    return __builtin_bit_cast(float, u);
}

// f32 -> OCP e4m3fn, RNE, with subnormals and 448 clamp
__device__ __forceinline__ unsigned char f32_e4m3(float x){
    unsigned b = __builtin_bit_cast(unsigned, x);
    unsigned s = b >> 31;
    float a = fabsf(x);
    if (a >= 448.f) return (unsigned char)((s<<7) | 0x7E);
    int E = (int)((b>>23)&255) - 127;
    if (E < -6) E = -6;
    int qi = (int)rintf(a * exp2f((float)(3 - E)));
    if (qi >= 16){ qi >>= 1; ++E; }
    if (qi == 0) return (unsigned char)(s<<7);
    unsigned mag = (qi >= 8) ? ((((unsigned)(E + 7)) << 3) | (unsigned)(qi - 8))
                             : (unsigned)qi;
    return (unsigned char)((s<<7) | mag);
}

__device__ __forceinline__ float sigm(float x){
    return __builtin_amdgcn_rcpf(1.f + __expf(-x));
}
__device__ __forceinline__ float tanh_(float x){
    float e = __expf(2.f*x);
    return 1.f - 2.f*__builtin_amdgcn_rcpf(e + 1.f);
}

__device__ __forceinline__ void lds_load16(void* lds, const void* g){
    __builtin_amdgcn_global_load_lds(
        (const __attribute__((address_space(1))) void*)g,
        (__attribute__((address_space(3))) void*)lds, 16, 0, 0);
}

// LDS-only barrier: no vmcnt(0) drain (h-exchange is pure LDS; global stores stay async)
__device__ __forceinline__ void barrier_lds(){
    asm volatile("s_waitcnt lgkmcnt(0)" ::: "memory");
    __builtin_amdgcn_s_barrier();
    __builtin_amdgcn_sched_barrier(0);
}

__device__ __forceinline__ void store_out(unsigned short* p, float v){ *p = f2bf(v); }
__device__ __forceinline__ void store_out(float* p, float v){ *p = v; }

// ---------------- embedding gather -> fp8 ----------------
__global__ void k_embed(const int* __restrict__ ids, const float* __restrict__ emb,
                        unsigned char* __restrict__ x0){
    int bt = blockIdx.x;
    int e  = threadIdx.x;
    int id = ids[bt];
    x0[(size_t)bt*E_ + e] = f32_e4m3(emb[(size_t)id*E_ + e]);
}

// ---------------- w_ih: permute rows into packed order -> fp8 ----------------
// packed col p = dir*1024 + w*128 + uh*64 + g*16 + ul  <->  orig row = dir*1024 + g*256 + w*32 + uh*16 + ul
__global__ void k_pack_wih(const float* __restrict__ in, unsigned char* __restrict__ out, int K){
    int p = blockIdx.y;
    int k = blockIdx.x*256 + threadIdx.x;
    int dirc = p >> 10, pp = p & 1023;
    int wv = pp >> 7, rem = pp & 127;
    int uh = (rem >> 6) & 1, g = (rem >> 4) & 3, ulx = rem & 15;
    int orig = dirc*1024 + g*256 + wv*32 + uh*16 + ulx;
    out[(size_t)p*K + k] = f32_e4m3(in[(size_t)orig*K + k]);
}

__global__ void k_pack_bias(const float* __restrict__ b, float* __restrict__ bp){
    int p = blockIdx.x*256 + threadIdx.x;   // 2048
    int dirc = p >> 10, pp = p & 1023;
    int wv = pp >> 7, rem = pp & 127;
    int uh = (rem >> 6) & 1, g = (rem >> 4) & 3, ulx = rem & 15;
    int orig = dirc*1024 + g*256 + wv*32 + uh*16 + ulx;
    bp[p] = b[orig];
}

// ---------------- w_hh -> fp8 MFMA B-fragment buffer (K=128 f8f6f4 frags) ----------------
// layout (32-byte units): [dir2][w8][kt2][g4][uh2][lane64]
// byte j of unit = W[dir][g*256 + w*32 + uh*16 + (lane&15)][kt*128 + (lane>>4)*32 + j]
__global__ void k_pack_wfp8(const float* __restrict__ whh, unsigned char* __restrict__ wpk){
    int idx = blockIdx.x*256 + threadIdx.x;   // 16384 total
    int lane = idx & 63;
    int uh   = (idx >> 6) & 1;
    int g    = (idx >> 7) & 3;
    int kt   = (idx >> 9) & 1;
    int wv   = (idx >> 10) & 7;
    int dir  = (idx >> 13) & 1;
    int ulx = lane & 15, hi4 = lane >> 4;
    int row = g*256 + wv*32 + uh*16 + ulx;
    int k0 = kt*128 + hi4*32;
    const float* src = whh + ((size_t)dir*G4 + row)*H_ + k0;
    unsigned char* dst = wpk + (size_t)idx*32;
    #pragma unroll
    for (int q = 0; q < 32; ++q) dst[q] = f32_e4m3(src[q]);
}

// ---------------- fp8 MX GEMM: C[M][N] = A[M][K]*Bm[N][K]^T + bias[N] (bf16 out) ----------------
// LDS tile layout: [ks4][row128][32B], 16B-granule XOR swizzle: j ^= (row&4)<<2
__global__ __launch_bounds__(256) void k_gemm_fp8(const unsigned char* __restrict__ A,
                                                  const unsigned char* __restrict__ Bm,
                                                  const float* __restrict__ bias,
                                                  unsigned short* __restrict__ C,
                                                  int M, int N, int K){
    __shared__ __align__(16) unsigned char As[16384];
    __shared__ __align__(16) unsigned char Bs[16384];
    int tid = threadIdx.x, lane = tid & 63, w = tid >> 6;
    int wm = w >> 1, wn = w & 1;
    int tileM = blockIdx.y * 128, tileN = blockIdx.x * 128;
    f32x4 acc[4][4] = {};
    for (int k0 = 0; k0 < K; k0 += 128){
        #pragma unroll
        for (int p = 0; p < 4; ++p){
            int idx = (p*256 + tid)*16;
            int ks = idx >> 12, rem = idx & 4095, row = rem >> 5;
            int jsrc = (rem & 16) ^ ((row & 4) << 2);
            lds_load16((char*)As + idx, A + (size_t)(tileM + row)*K + k0 + ks*32 + jsrc);
            lds_load16((char*)Bs + idx, Bm + (size_t)(tileN + row)*K + k0 + ks*32 + jsrc);
        }
        __syncthreads();   // drains vmcnt for global_load_lds
        int ks = lane >> 4, m15 = lane & 15;
        i32x8 af[4], bfv[4];
        #pragma unroll
        for (int mf = 0; mf < 4; ++mf){
            int r = wm*64 + mf*16 + m15;
            int base = ks*4096 + r*32, sw = (r & 4) << 2;
            i32x4 lo = *(const i32x4*)((const char*)As + base + sw);
            i32x4 hi = *(const i32x4*)((const char*)As + base + (16 ^ sw));
            af[mf] = __builtin_shufflevector(lo, hi, 0,1,2,3,4,5,6,7);
        }
        #pragma unroll
        for (int nf = 0; nf < 4; ++nf){
            int r = wn*64 + nf*16 + m15;
            int base = ks*4096 + r*32, sw = (r & 4) << 2;
            i32x4 lo = *(const i32x4*)((const char*)Bs + base + sw);
            i32x4 hi = *(const i32x4*)((const char*)Bs + base + (16 ^ sw));
            bfv[nf] = __builtin_shufflevector(lo, hi, 0,1,2,3,4,5,6,7);
        }
        #pragma unroll
        for (int mf = 0; mf < 4; ++mf)
            #pragma unroll
            for (int nf = 0; nf < 4; ++nf)
                acc[mf][nf] = __builtin_amdgcn_mfma_scale_f32_16x16x128_f8f6f4(
                                  af[mf], bfv[nf], acc[mf][nf],
                                  0, 0, 0, 0x7f7f7f7f, 0, 0x7f7f7f7f);
        barrier_lds();     // protect LDS reads from next staging overwrite (no vmcnt drain)
    }
    #pragma unroll
    for (int mf = 0; mf < 4; ++mf){
        #pragma unroll
        for (int nf = 0; nf < 4; ++nf){
            int row0 = tileM + wm*64 + mf*16 + (lane >> 4)*4;
            int col  = tileN + wn*64 + nf*16 + (lane & 15);
            float bv = bias[col];
            #pragma unroll
            for (int r = 0; r < 4; ++r)
                C[(size_t)(row0 + r)*N + col] = f2bf(acc[mf][nf][r] + bv);
        }
    }
}

// ---------------- LSTM recurrence, MX-scaled fp8 MFMA (K=128), weights register-resident ----------------
// grid = 32 blocks: blk&1 = dir, blk>>1 = bg(0..15); block = 512 thr (8 waves).
// Wave w owns units [w*32, w*32+32) x 4 gates. Batches = bg*4 + (lane>>4) at A/D row (lane>>4)*4.
// gx: [BT][2048] packed cols, bias pre-added. wpk: fp8 K=128 frags. out: [BT][512].
template<typename OutT>
__global__ __launch_bounds__(512, 2)
void k_rec_mfma(const unsigned short* __restrict__ gx,
                const unsigned char* __restrict__ wpk,
                OutT* __restrict__ out){
    int blk = blockIdx.x;
    int dir = blk & 1, bg = blk >> 1;
    int tid = threadIdx.x, lane = tid & 63, w = tid >> 6;
    int ul = lane & 15, hi4 = lane >> 4;
    int batch = bg*4 + hi4;

    // h state: fp8, [buf2][kb32][Arow16][8B]; batch q lives at Arow q*4; h[unit u] at kb=u>>3, byte=u&7
    __shared__ __align__(16) unsigned char hlds[2][32][16][8];
    {
        unsigned long long* hz = (unsigned long long*)hlds;
        for (int i = tid; i < 1024; i += 512) hz[i] = 0ull;
    }

    // register-resident W fragments: [kt2][g4][uh2], 32 B/lane each
    i32x8 wf[2][4][2];
    {
        const i32x8* wb = (const i32x8*)wpk;
        #pragma unroll
        for (int kt = 0; kt < 2; ++kt)
            #pragma unroll
            for (int g = 0; g < 4; ++g)
                #pragma unroll
                for (int uh = 0; uh < 2; ++uh)
                    wf[kt][g][uh] = wb[((((size_t)(dir*8 + w)*2 + kt)*4 + g)*2 + uh)*64 + lane];
    }
    __syncthreads();

    const unsigned short* gp = gx + (size_t)(batch*T_ + (dir ? T_-1 : 0))*N2
                                  + dir*1024 + w*128 + ul;
    ptrdiff_t dstep = dir ? -(ptrdiff_t)N2 : (ptrdiff_t)N2;

    unsigned short gxr[8];
    #pragma unroll
    for (int uh = 0; uh < 2; ++uh)
        #pragma unroll
        for (int g = 0; g < 4; ++g)
            gxr[uh*4+g] = gp[uh*64 + g*16];

    float c0 = 0.f, c1 = 0.f;
    int u0 = w*32 + ul, u1 = u0 + 16;
    OutT* ob = out + (size_t)batch*T_*512 + dir*256;

    for (int s = 0; s < T_; ++s){
        int buf = s & 1;
        f32x4 acc[4][2];
        #pragma unroll
        for (int g = 0; g < 4; ++g)
            #pragma unroll
            for (int uh = 0; uh < 2; ++uh)
                acc[g][uh] = (f32x4){ bf2f(gxr[uh*4+g]), 0.f, 0.f, 0.f };

        // prefetch next step's gx
        gp += dstep;
        unsigned short gxn[8];
        #pragma unroll
        for (int uh = 0; uh < 2; ++uh)
            #pragma unroll
            for (int g = 0; g < 4; ++g)
                gxn[uh*4+g] = gp[uh*64 + g*16];

        // MFMA: gates += h @ W^T   (2 K-tiles of 128)
        const unsigned long long* hrow = (const unsigned long long*)&hlds[buf][0][0][0];
        #pragma unroll
        for (int kt = 0; kt < 2; ++kt){
            unsigned long long a0 = hrow[(kt*16 + hi4*4 + 0)*16 + ul];
            unsigned long long a1 = hrow[(kt*16 + hi4*4 + 1)*16 + ul];
            unsigned long long a2 = hrow[(kt*16 + hi4*4 + 2)*16 + ul];
            unsigned long long a3 = hrow[(kt*16 + hi4*4 + 3)*16 + ul];
            i32x8 af = (i32x8){ (int)a0, (int)(a0>>32), (int)a1, (int)(a1>>32),
                                (int)a2, (int)(a2>>32), (int)a3, (int)(a3>>32) };
            #pragma unroll
            for (int g = 0; g < 4; ++g)
                #pragma unroll
                for (int uh = 0; uh < 2; ++uh)
                    acc[g][uh] = __builtin_amdgcn_mfma_scale_f32_16x16x128_f8f6f4(
                                     af, wf[kt][g][uh], acc[g][uh],
                                     0, 0, 0, 0x7f7f7f7f, 0, 0x7f7f7f7f);
        }

        // cell updates: 2 cells/lane (units u0, u1)
        int tt = dir ? (T_-1-s) : s;
        float h0, h1;
        {
            float xi = acc[0][0][0], xf = acc[1][0][0], xg = acc[2][0][0], xo = acc[3][0][0];
            c0 = sigm(xf)*c0 + sigm(xi)*tanh_(xg);
            h0 = sigm(xo)*tanh_(c0);
        }
        {
            float xi = acc[0][1][0], xf = acc[1][1][0], xg = acc[2][1][0], xo = acc[3][1][0];
            c1 = sigm(xf)*c1 + sigm(xi)*tanh_(xg);
            h1 = sigm(xo)*tanh_(c1);
        }

        unsigned char hb0, hb1;
#if __has_builtin(__builtin_amdgcn_cvt_pk_fp8_f32)
        {
            int pk = __builtin_amdgcn_cvt_pk_fp8_f32(h0, h1, 0, false);
            hb0 = (unsigned char)(pk & 0xff);
            hb1 = (unsigned char)((pk >> 8) & 0xff);
        }
#else
        hb0 = f32_e4m3(h0); hb1 = f32_e4m3(h1);
#endif
        hlds[buf^1][u0>>3][hi4*4][u0&7] = hb0;
        hlds[buf^1][u1>>3][hi4*4][u1&7] = hb1;

        if constexpr (sizeof(OutT) == 1){
            ((unsigned char*)ob)[(size_t)tt*512 + u0] = hb0;
            ((unsigned char*)ob)[(size_t)tt*512 + u1] = hb1;
        } else {
            store_out(&ob[(size_t)tt*512 + u0], h0);
            store_out(&ob[(size_t)tt*512 + u1], h1);
        }

        #pragma unroll
        for (int i = 0; i < 8; ++i) gxr[i] = gxn[i];
        barrier_lds();   // LDS-only: don't drain the async global h stores / gx prefetch
    }
}

// ---------------- final linear ----------------
__global__ __launch_bounds__(256) void k_linear(const float* __restrict__ x,
                                                const float* __restrict__ w,
                                                const float* __restrict__ bias,
                                                float* __restrict__ em){
    int wv = threadIdx.x >> 6, lane = threadIdx.x & 63;
    int bt = blockIdx.x*4 + wv;
    const float4* xp = (const float4*)(x + (size_t)bt*(2*H_) + lane*8);
    float4 xa = xp[0], xb = xp[1];
    #pragma unroll
    for (int l = 0; l < L_; ++l){
        const float4* wp = (const float4*)(w + (size_t)l*(2*H_) + lane*8);
        float4 wa = wp[0], wb = wp[1];
        float p = xa.x*wa.x + xa.y*wa.y + xa.z*wa.z + xa.w*wa.w
                + xb.x*wb.x + xb.y*wb.y + xb.z*wb.z + xb.w*wb.w;
        #pragma unroll
        for (int o = 32; o; o >>= 1) p += __shfl_xor(p, o);
        if (lane == 0) em[(size_t)bt*L_ + l] = p + bias[l];
    }
}

// ---------------- CRF NLL ----------------
__global__ void k_crf(const float* __restrict__ em, const int* __restrict__ labels,
                      const int* __restrict__ mask, const float* __restrict__ trans,
                      const float* __restrict__ st, const float* __restrict__ et,
                      float* __restrict__ out){
    int b = blockIdx.x, lane = threadIdx.x;
    __shared__ float tr[L_*L_];
    for (int i = lane; i < L_*L_; i += 64) tr[i] = trans[i];
    __syncthreads();
    const float* e  = em + (size_t)b*T_*L_;
    const int* lab  = labels + b*T_;
    const int* mk   = mask + b*T_;
    float sc = 0.f; int msum = 0;
    for (int t = lane; t < T_; t += 64){
        msum += mk[t];
        if (t >= 1)
            sc += (tr[lab[t-1]*L_ + lab[t]] + e[t*L_ + lab[t]]) * (float)mk[t];
    }
    #pragma unroll
    for (int o = 32; o; o >>= 1){ sc += __shfl_xor(sc, o); msum += __shfl_xor(msum, o); }
    int lj = lane < L_ ? lane : 0;
    float alpha = (lane < L_) ? (st[lj] + e[lj]) : -3.0e38f;
    for (int t = 1; t < T_; ++t){
        float v[L_]; float m = -3.0e38f;
        #pragma unroll
        for (int i = 0; i < L_; ++i){
            float ai = __shfl(alpha, i);
            v[i] = ai + tr[i*L_ + lj];
            m = fmaxf(m, v[i]);
        }
        float ssum = 0.f;
        #pragma unroll
        for (int i = 0; i < L_; ++i) ssum += __expf(v[i] - m);
        float nw = m + __logf(ssum) + e[t*L_ + lj];
        if (lane < L_ && mk[t] > 0) alpha = nw;
    }
    float av = (lane < L_) ? alpha + et[lj] : -3.0e38f;
    float m2 = av;
    #pragma unroll
    for (int o = 32; o; o >>= 1) m2 = fmaxf(m2, __shfl_xor(m2, o));
    float s2 = (lane < L_) ? __expf(av - m2) : 0.f;
    #pragma unroll
    for (int o = 32; o; o >>= 1) s2 += __shfl_xor(s2, o);
    if (lane == 0){
        float logZ = m2 + __logf(s2);
        int last = msum - 1;
        float score = sc + st[lab[0]] + e[lab[0]] + et[lab[last]];
        atomicAdd(out, (logZ - score) * (1.f/(float)B_));
    }
}

extern "C" void kernel_launch(void* const* d_in, const int* in_sizes, int n_in,
                              void* d_out, int out_size, void* d_ws, size_t ws_size,
                              hipStream_t stream){
    (void)in_sizes; (void)n_in; (void)out_size; (void)ws_size;
    const int*   ids    = (const int*)d_in[0];
    const int*   amask  = (const int*)d_in[1];
    const int*   labels = (const int*)d_in[2];
    const float* emb    = (const float*)d_in[3];
    const float* w_ih0  = (const float*)d_in[4];
    const float* w_hh0  = (const float*)d_in[5];
    const float* b0     = (const float*)d_in[6];
    const float* w_ih1  = (const float*)d_in[7];
    const float* w_hh1  = (const float*)d_in[8];
    const float* b1     = (const float*)d_in[9];
    const float* lin_w  = (const float*)d_in[10];
    const float* lin_b  = (const float*)d_in[11];
    const float* trans  = (const float*)d_in[12];
    const float* st     = (const float*)d_in[13];
    const float* et     = (const float*)d_in[14];
    float* out = (float*)d_out;

    char* ws = (char*)d_ws;
    size_t o = 0;
    auto alloc = [&](size_t bytes)->char*{
        char* p = ws + o; o = (o + bytes + 255) & ~(size_t)255; return p;
    };
    unsigned char*  x0    = (unsigned char*)alloc((size_t)BT*E_);       // 8.4 MB fp8
    unsigned char*  wih0p = (unsigned char*)alloc((size_t)N2*E_);       // fp8
    unsigned char*  wih1p = (unsigned char*)alloc((size_t)N2*512);      // fp8
    unsigned char*  wpk0  = (unsigned char*)alloc(16384*32);
    unsigned char*  wpk1  = (unsigned char*)alloc(16384*32);
    float*          bp0   = (float*)alloc(N2*4);
    float*          bp1   = (float*)alloc(N2*4);
    unsigned short* gx    = (unsigned short*)alloc((size_t)BT*N2*2);    // 134 MB bf16
    unsigned char*  xc1   = (unsigned char*)alloc((size_t)BT*512);      // 16.8 MB fp8
    float*          xc2   = (float*)alloc((size_t)BT*512*4);            // 67 MB
    float*          em    = (float*)alloc((size_t)BT*L_*4 + 1024);

    hipMemsetAsync(d_out, 0, sizeof(float), stream);

    k_pack_wih<<<dim3(E_/256, N2), 256, 0, stream>>>(w_ih0, wih0p, E_);
    k_pack_wih<<<dim3(512/256, N2), 256, 0, stream>>>(w_ih1, wih1p, 512);
    k_pack_bias<<<N2/256, 256, 0, stream>>>(b0, bp0);
    k_pack_bias<<<N2/256, 256, 0, stream>>>(b1, bp1);
    k_pack_wfp8<<<16384/256, 256, 0, stream>>>(w_hh0, wpk0);
    k_pack_wfp8<<<16384/256, 256, 0, stream>>>(w_hh1, wpk1);
    k_embed<<<BT, E_, 0, stream>>>(ids, emb, x0);

    k_gemm_fp8<<<dim3(N2/128, BT/128), 256, 0, stream>>>(x0, wih0p, bp0, gx, BT, N2, E_);
    k_rec_mfma<unsigned char><<<32, 512, 0, stream>>>(gx, wpk0, xc1);
    k_gemm_fp8<<<dim3(N2/128, BT/128), 256, 0, stream>>>(xc1, wih1p, bp1, gx, BT, N2, 512);
    k_rec_mfma<float><<<32, 512, 0, stream>>>(gx, wpk1, xc2);

    k_linear<<<BT/4, 256, 0, stream>>>(xc2, lin_w, lin_b, em);
    k_crf<<<B_, 64, 0, stream>>>(em, labels, amask, trans, st, et, out);
}